// Round 14
// baseline (776.210 us; speedup 1.0000x reference)
//
#include <hip/hip_runtime.h>
#include <stdint.h>

typedef unsigned short u16;
typedef unsigned int u32;
typedef __attribute__((ext_vector_type(8))) short short8;
typedef __attribute__((ext_vector_type(4))) float f32x4;

// ---------- helpers ----------
__device__ __forceinline__ u16 f2bf(float f) {
  u32 u = __builtin_bit_cast(u32, f);
  u32 r = u + 0x7FFFu + ((u >> 16) & 1u);
  return (u16)(r >> 16);
}

__device__ __forceinline__ void gl_lds16(const void* g, void* l) {
  __builtin_amdgcn_global_load_lds((__attribute__((address_space(1))) void*)g,
                                   (__attribute__((address_space(3))) void*)l,
                                   16, 0, 0);
}

// tanh-form GELU (~13 VALU inst; |err| <= ~3e-3, verified absmax unchanged)
__device__ __forceinline__ float gelu_fast(float v) {
  float u = 0.7978845608028654f * (v + 0.044715f * v * v * v);
  float a = fabsf(u);
  float e = __expf(-2.0f * a);
  float t = (1.0f - e) / (1.0f + e);     // tanh(|u|)
  float th = copysignf(t, u);
  return 0.5f * v * (1.0f + th);
}

// ---------- f32 -> bf16 convert (weights) ----------
__global__ __launch_bounds__(256) void cvt_bf16(const float* __restrict__ in,
                                                u16* __restrict__ out, int n4) {
  int idx = blockIdx.x * 256 + threadIdx.x;
  if (idx < n4) {
    float4 v = ((const float4*)in)[idx];
    u32 lo = (u32)f2bf(v.x) | ((u32)f2bf(v.y) << 16);
    u32 hi = (u32)f2bf(v.z) | ((u32)f2bf(v.w) << 16);
    ((uint2*)out)[idx] = make_uint2(lo, hi);
  }
}

// ---------- LN1 + roll + window partition gather ----------
__global__ __launch_bounds__(256) void ln1_kernel(const float* __restrict__ x,
                                                  const float* __restrict__ g,
                                                  const float* __restrict__ bta,
                                                  u16* __restrict__ xcat) {
  int wave = threadIdx.x >> 6, lane = threadIdx.x & 63;
  int row = blockIdx.x * 4 + wave;   // 0..50815
  const float* src;
  bool do_ln;
  if (row < 640) {
    int bb = row / 10, p = row - bb * 10;
    src = x + ((size_t)bb * 794 + p) * 512;
    do_ln = false;
  } else {
    int r2 = row - 640;
    int i = r2 / 49, t = r2 - i * 49;
    int bb = i >> 4, nw = i & 15;
    int tr = t / 7, tc = t - tr * 7;
    int hh = (nw >> 2) * 7 + tr + 3; if (hh >= 28) hh -= 28;
    int ww = (nw & 3) * 7 + tc + 3;  if (ww >= 28) ww -= 28;
    src = x + ((size_t)bb * 794 + 10 + hh * 28 + ww) * 512;
    do_ln = true;
  }
  float4 v0 = ((const float4*)src)[lane * 2];
  float4 v1 = ((const float4*)src)[lane * 2 + 1];
  float vals[8] = {v0.x, v0.y, v0.z, v0.w, v1.x, v1.y, v1.z, v1.w};
  u16 ob[8];
  if (do_ln) {
    float s = 0.f, s2 = 0.f;
#pragma unroll
    for (int j = 0; j < 8; ++j) { s += vals[j]; s2 += vals[j] * vals[j]; }
#pragma unroll
    for (int o = 32; o > 0; o >>= 1) { s += __shfl_xor(s, o); s2 += __shfl_xor(s2, o); }
    float mu = s * (1.0f / 512.0f);
    float var = s2 * (1.0f / 512.0f) - mu * mu;
    float inv = rsqrtf(var + 1e-5f);
    float4 ga = ((const float4*)g)[lane * 2], gb = ((const float4*)g)[lane * 2 + 1];
    float4 ba = ((const float4*)bta)[lane * 2], bb2 = ((const float4*)bta)[lane * 2 + 1];
    float gv[8] = {ga.x, ga.y, ga.z, ga.w, gb.x, gb.y, gb.z, gb.w};
    float bv[8] = {ba.x, ba.y, ba.z, ba.w, bb2.x, bb2.y, bb2.z, bb2.w};
#pragma unroll
    for (int j = 0; j < 8; ++j) ob[j] = f2bf((vals[j] - mu) * inv * gv[j] + bv[j]);
  } else {
#pragma unroll
    for (int j = 0; j < 8; ++j) ob[j] = f2bf(vals[j]);
  }
  u32 w0 = (u32)ob[0] | ((u32)ob[1] << 16);
  u32 w1 = (u32)ob[2] | ((u32)ob[3] << 16);
  u32 w2 = (u32)ob[4] | ((u32)ob[5] << 16);
  u32 w3 = (u32)ob[6] | ((u32)ob[7] << 16);
  ((uint4*)(xcat + (size_t)row * 512))[lane] = make_uint4(w0, w1, w2, w3);
}

// ---------- LN2 (plain rows) ----------
__global__ __launch_bounds__(256) void ln2_kernel(const float* __restrict__ xn,
                                                  const float* __restrict__ g,
                                                  const float* __restrict__ bta,
                                                  u16* __restrict__ outb) {
  int wave = threadIdx.x >> 6, lane = threadIdx.x & 63;
  size_t row = (size_t)blockIdx.x * 4 + wave;
  const float* src = xn + row * 512;
  float4 v0 = ((const float4*)src)[lane * 2];
  float4 v1 = ((const float4*)src)[lane * 2 + 1];
  float vals[8] = {v0.x, v0.y, v0.z, v0.w, v1.x, v1.y, v1.z, v1.w};
  float s = 0.f, s2 = 0.f;
#pragma unroll
  for (int j = 0; j < 8; ++j) { s += vals[j]; s2 += vals[j] * vals[j]; }
#pragma unroll
  for (int o = 32; o > 0; o >>= 1) { s += __shfl_xor(s, o); s2 += __shfl_xor(s2, o); }
  float mu = s * (1.0f / 512.0f);
  float var = s2 * (1.0f / 512.0f) - mu * mu;
  float inv = rsqrtf(var + 1e-5f);
  float4 ga = ((const float4*)g)[lane * 2], gb = ((const float4*)g)[lane * 2 + 1];
  float4 ba = ((const float4*)bta)[lane * 2], bb2 = ((const float4*)bta)[lane * 2 + 1];
  float gv[8] = {ga.x, ga.y, ga.z, ga.w, gb.x, gb.y, gb.z, gb.w};
  float bv[8] = {ba.x, ba.y, ba.z, ba.w, bb2.x, bb2.y, bb2.z, bb2.w};
  u16 ob[8];
#pragma unroll
  for (int j = 0; j < 8; ++j) ob[j] = f2bf((vals[j] - mu) * inv * gv[j] + bv[j]);
  u32 w0 = (u32)ob[0] | ((u32)ob[1] << 16);
  u32 w1 = (u32)ob[2] | ((u32)ob[3] << 16);
  u32 w2 = (u32)ob[4] | ((u32)ob[5] << 16);
  u32 w3 = (u32)ob[6] | ((u32)ob[7] << 16);
  ((uint4*)(outb + row * 512))[lane] = make_uint4(w0, w1, w2, w3);
}

// ---------- 256x256 bf16 GEMM, m201 8-phase template (BK=64, half = K-half) ----------
// A: MxK row-major bf16, Wt: NxK row-major bf16 (B^T).
// 8 waves (2M x 4N), wave-tile 128x64, acc[8][4]. LDS: 8 half-slots x 16 KB (128 KB);
// global half H = 4*kt + {0:A-ks0, 1:B-ks0, 2:A-ks1, 3:B-ks1}, slot = H&7; a half is
// 256 rows x 32 k. Swizzle (both sides, rule 21): phys 16B-slot = slot ^ (row&3).
// Phase (kt,ks,mp): {bv[4] read if mp==0 (reused at mp==1) + av[4] read ; stage one
// half at lead 5 (2 gl_lds) ; vmcnt(6)=3 halves in flight ; bar ; lgkm0+sched_bar ;
// setprio(1) 16 MFMA setprio(0) ; bar}. Ledger: reads at P need halves <= P+1;
// vmcnt(6) at P-1 certifies staged <= (P+5)-... = P+1  (lead 5 - 3 in flight - 1). Tail
// ramps 6->4->2->0; prologue stages halves 0..4 + vmcnt(6) (certifies halves 0,1).
#define PHASE(MB, RD_BV, HA_SLOT, HB_SLOT, DO_STAGE, SH, VMC)                         \
  do {                                                                                \
    short8 av[4];                                                                     \
    if (RD_BV) {                                                                      \
      _Pragma("unroll") for (int n = 0; n < 4; ++n) {                                 \
        int row = wnW * 64 + n * 16 + lr;                                             \
        bv[n] = *(const short8*)&Hlds[HB_SLOT][row * 32 + swzr];                      \
      }                                                                               \
    }                                                                                 \
    _Pragma("unroll") for (int mm = 0; mm < 4; ++mm) {                                \
      int row = wm * 128 + ((MB) + mm) * 16 + lr;                                     \
      av[mm] = *(const short8*)&Hlds[HA_SLOT][row * 32 + swzr];                       \
    }                                                                                 \
    if (DO_STAGE) {                                                                   \
      const int hh = (SH);                                                            \
      const int slot = hh & 7;                                                        \
      const int r4 = hh & 3;                                                          \
      const size_t koff = (size_t)((hh >> 2) * 64 + ((r4 >> 1) & 1) * 32);            \
      const u16* p = ((r4 & 1) ? Bsrc : Asrc) + koff;                                 \
      u16* d = &Hlds[slot][tid * 8];                                                  \
      gl_lds16(p, d);                                                                 \
      gl_lds16(p + halfK, d + 4096);                                                  \
    }                                                                                 \
    asm volatile("s_waitcnt vmcnt(" #VMC ")" ::: "memory");                           \
    __builtin_amdgcn_s_barrier();                                                     \
    asm volatile("s_waitcnt lgkmcnt(0)" ::: "memory");                                \
    __builtin_amdgcn_sched_barrier(0);                                                \
    __builtin_amdgcn_s_setprio(1);                                                    \
    _Pragma("unroll") for (int mm = 0; mm < 4; ++mm)                                  \
      _Pragma("unroll") for (int n = 0; n < 4; ++n)                                   \
        acc[(MB) + mm][n] =                                                           \
            __builtin_amdgcn_mfma_f32_16x16x32_bf16(av[mm], bv[n], acc[(MB) + mm][n], \
                                                    0, 0, 0);                         \
    __builtin_amdgcn_s_setprio(0);                                                    \
    __builtin_amdgcn_s_barrier();                                                     \
  } while (0)

template <int EPI>
__global__ __launch_bounds__(512, 2) void gemm8p(const u16* __restrict__ A,
                                                 const u16* __restrict__ Wt,
                                                 const float* __restrict__ bias,
                                                 u16* __restrict__ outb,
                                                 float* __restrict__ outf,
                                                 const float* __restrict__ res,
                                                 int M, int N, int K, int Ntiles) {
  __shared__ __align__(16) u16 Hlds[8][8192];   // 128 KB
  const int tid = threadIdx.x;
  const int lane = tid & 63;
  const int wv = tid >> 6;            // 0..7
  const int wm = wv >> 2;             // 0..1  (M strip of 128)
  const int wnW = wv & 3;             // 0..3  (N strip of 64)
  const int lr = lane & 15;
  const int qh = lane >> 4;           // 0..3 (16B k-slot within 32-k half)
  const int swzr = (qh ^ (lr & 3)) << 3;   // swizzled read slot offset (elements)

  // bijective XCD swizzle (m204), N-fastest
  const int nwg = gridDim.x;
  const int qx = nwg >> 3, rx = nwg & 7;
  const int xcd = blockIdx.x & 7, local = blockIdx.x >> 3;
  const int swz = (xcd < rx ? xcd * (qx + 1) : rx * (qx + 1) + (xcd - rx) * qx) + local;
  const int mt = swz / Ntiles, nt = swz - mt * Ntiles;
  const int tm = mt << 8, tn = nt << 8;   // 256x256 tile

  f32x4 acc[8][4];
#pragma unroll
  for (int m = 0; m < 8; ++m)
#pragma unroll
    for (int n = 0; n < 4; ++n)
#pragma unroll
      for (int e = 0; e < 4; ++e) acc[m][n][e] = 0.f;

  // staging map: thread -> row srow = tid>>2 (0..127; +128 for 2nd gl_lds), phys slot tid&3
  const int srow = tid >> 2;
  const int scol = ((tid & 3) ^ (srow & 3)) << 3;   // pre-swizzled source col (elements)
  const u16* Asrc = A + (size_t)(tm + srow) * K + scol;
  const u16* Bsrc = Wt + (size_t)(tn + wnW * 0 + srow) * K + scol;  // B rows = out cols
  const size_t halfK = (size_t)128 * K;

  const int NT = K >> 6;   // K-tiles of 64: 8 (K=512) or 32 (K=2048)

  // prologue: stage halves 0..4, certify halves 0,1 (vmcnt(6) leaves 3 halves in flight)
  {
#pragma unroll
    for (int hh = 0; hh < 5; ++hh) {
      const int slot = hh & 7;
      const int r4 = hh & 3;
      const size_t koff = (size_t)((hh >> 2) * 64 + ((r4 >> 1) & 1) * 32);
      const u16* p = ((r4 & 1) ? Bsrc : Asrc) + koff;
      u16* d = &Hlds[slot][tid * 8];
      gl_lds16(p, d);
      gl_lds16(p + halfK, d + 4096);
    }
    asm volatile("s_waitcnt vmcnt(6)" ::: "memory");
    __builtin_amdgcn_s_barrier();
  }

  short8 bv[4];
  for (int kt = 0; kt < NT - 2; ++kt) {
    const int P = kt << 2;
    const int sA0 = P & 7, sB0 = (P + 1) & 7, sA1 = (P + 2) & 7, sB1 = (P + 3) & 7;
    PHASE(0, true,  sA0, sB0, true, P + 5, 6);
    PHASE(4, false, sA0, sB0, true, P + 6, 6);
    PHASE(0, true,  sA1, sB1, true, P + 7, 6);
    PHASE(4, false, sA1, sB1, true, P + 8, 6);
  }
  {  // kt = NT-2: last stage at phase P+2 (half 4NT-1); ramp begins
    const int P = (NT - 2) << 2;
    const int sA0 = P & 7, sB0 = (P + 1) & 7, sA1 = (P + 2) & 7, sB1 = (P + 3) & 7;
    PHASE(0, true,  sA0, sB0, true, P + 5, 6);
    PHASE(4, false, sA0, sB0, true, P + 6, 6);
    PHASE(0, true,  sA1, sB1, true, P + 7, 6);
    PHASE(4, false, sA1, sB1, false, 0, 4);
  }
  {  // kt = NT-1: drain 2 -> 0
    const int P = (NT - 1) << 2;
    const int sA0 = P & 7, sB0 = (P + 1) & 7, sA1 = (P + 2) & 7, sB1 = (P + 3) & 7;
    PHASE(0, true,  sA0, sB0, false, 0, 2);
    PHASE(4, false, sA0, sB0, false, 0, 0);
    PHASE(0, true,  sA1, sB1, false, 0, 0);
    PHASE(4, false, sA1, sB1, false, 0, 0);
  }

  // ---------- epilogue ----------
  float bcol[4];
#pragma unroll
  for (int n = 0; n < 4; ++n) bcol[n] = bias[tn + wnW * 64 + n * 16 + lr];

#pragma unroll
  for (int m = 0; m < 8; ++m) {
#pragma unroll
    for (int r2 = 0; r2 < 4; ++r2) {
      int grow = tm + wm * 128 + m * 16 + qh * 4 + r2;
      if (grow >= M) continue;                    // QKV tail M-tile
      if (EPI == 1) {
        int i = grow / 49, t = grow - i * 49;
        int bb = i >> 4, nw = i & 15;
        int tr = t / 7, tc = t - tr * 7;
        int hh = (nw >> 2) * 7 + tr + 3; if (hh >= 28) hh -= 28;
        int ww = (nw & 3) * 7 + tc + 3;  if (ww >= 28) ww -= 28;
        size_t dstr = ((size_t)bb * 784 + hh * 28 + ww) * 512;
        size_t srcr = ((size_t)bb * 794 + 10 + hh * 28 + ww) * 512;
#pragma unroll
        for (int n = 0; n < 4; ++n) {
          int gcol = tn + wnW * 64 + n * 16 + lr;
          float v = acc[m][n][r2] + bcol[n];
          outf[dstr + gcol] = v + res[srcr + gcol];
        }
      } else {
#pragma unroll
        for (int n = 0; n < 4; ++n) {
          int gcol = tn + wnW * 64 + n * 16 + lr;
          float v = acc[m][n][r2] + bcol[n];
          if (EPI == 0) {
            outb[(size_t)grow * N + gcol] = f2bf(v);
          } else if (EPI == 2) {
            outb[(size_t)grow * N + gcol] = f2bf(gelu_fast(v));
          } else { // EPI == 3
            outf[(size_t)grow * N + gcol] = v + res[(size_t)grow * 512 + gcol];
          }
        }
      }
    }
  }
}

// ---------- fused window attention: one wave per (window, head) ----------
__global__ __launch_bounds__(64) void attn_kernel(const u16* __restrict__ Y,
                                                  const float* __restrict__ rpb,
                                                  u16* __restrict__ outp) {
  __shared__ __align__(16) u16 Plds[64 * 64];
  __shared__ __align__(16) u16 Vt[32 * 64];
  __shared__ float biasl[169];
  const int lane = threadIdx.x;
  const int i = blockIdx.x >> 4;
  const int hd = blockIdx.x & 15;
  const int bp = i & 63;           // reference quirk: prompt batch = i % B
  const int nw = i & 15;
  const int hi = nw >> 2, wi = nw & 3;
  const int lr = lane & 15;
  const int lk = (lane >> 4) * 8;

  for (int j = lane; j < 169; j += 64) biasl[j] = rpb[j * 16 + hd];

  short8 qf[4], kf[4];
#pragma unroll
  for (int m = 0; m < 4; ++m) {
    int t = m * 16 + lr;
    size_t r = (t < 10) ? (size_t)(bp * 10 + t) : (size_t)(640 + i * 49 + (t - 10));
    const u16* base = Y + r * 1536 + hd * 32 + lk;
    if (t < 59) {
      qf[m] = *(const short8*)(base);
      kf[m] = *(const short8*)(base + 512);
    } else {
#pragma unroll
      for (int e = 0; e < 8; ++e) { qf[m][e] = 0; kf[m][e] = 0; }
    }
  }
  {
    int t = lane;
    if (t < 59) {
      size_t r = (t < 10) ? (size_t)(bp * 10 + t) : (size_t)(640 + i * 49 + (t - 10));
      const u16* vp = Y + r * 1536 + 1024 + hd * 32;
      short8 vv0 = *(const short8*)(vp);
      short8 vv1 = *(const short8*)(vp + 8);
      short8 vv2 = *(const short8*)(vp + 16);
      short8 vv3 = *(const short8*)(vp + 24);
#pragma unroll
      for (int e = 0; e < 8; ++e) {
        Vt[e * 64 + t] = (u16)vv0[e];
        Vt[(8 + e) * 64 + t] = (u16)vv1[e];
        Vt[(16 + e) * 64 + t] = (u16)vv2[e];
        Vt[(24 + e) * 64 + t] = (u16)vv3[e];
      }
    } else {
      for (int d = 0; d < 32; ++d) Vt[d * 64 + t] = 0;
    }
  }

  f32x4 s[4][4];
#pragma unroll
  for (int m = 0; m < 4; ++m)
#pragma unroll
    for (int n = 0; n < 4; ++n)
#pragma unroll
      for (int r2 = 0; r2 < 4; ++r2) s[m][n][r2] = 0.f;
#pragma unroll
  for (int m = 0; m < 4; ++m)
#pragma unroll
    for (int n = 0; n < 4; ++n)
      s[m][n] = __builtin_amdgcn_mfma_f32_16x16x32_bf16(qf[m], kf[n], s[m][n], 0, 0, 0);

  __syncthreads();

  const float SCALE = 0.17677669529663687f;
  const int rgrp = lane >> 4;
#pragma unroll
  for (int m = 0; m < 4; ++m) {
#pragma unroll
    for (int r2 = 0; r2 < 4; ++r2) {
      int rn = m * 16 + rgrp * 4 + r2;   // query token
      int qa = rn - 10;
      int qra = qa / 7, qca = qa - qra * 7;
      int regA = 0;
      if (qa >= 0 && qa < 49) {
        int ha = hi * 7 + qra, wa = wi * 7 + qca;
        regA = (ha < 21 ? 0 : (ha < 25 ? 1 : 2)) * 3 + (wa < 21 ? 0 : (wa < 25 ? 1 : 2));
      }
      float vloc[4];
      float mx = -3.0e38f;
#pragma unroll
      for (int n = 0; n < 4; ++n) {
        int cm = n * 16 + lr;            // key token
        float v;
        if (cm >= 59) {
          v = -3.0e38f;
        } else {
          v = s[m][n][r2] * SCALE;
          if (rn >= 10 && rn < 59 && cm >= 10) {
            int kb = cm - 10;
            int krb = kb / 7, kcb = kb - krb * 7;
            v += biasl[(qra - krb + 6) * 13 + (qca - kcb + 6)];
            int hb = hi * 7 + krb, wb = wi * 7 + kcb;
            int regB = (hb < 21 ? 0 : (hb < 25 ? 1 : 2)) * 3 + (wb < 21 ? 0 : (wb < 25 ? 1 : 2));
            if (regA != regB) v -= 100.0f;
          }
        }
        vloc[n] = v;
        mx = fmaxf(mx, v);
      }
#pragma unroll
      for (int o = 8; o > 0; o >>= 1) mx = fmaxf(mx, __shfl_xor(mx, o));
      float sum = 0.f;
#pragma unroll
      for (int n = 0; n < 4; ++n) {
        float e = __expf(vloc[n] - mx);
        vloc[n] = e;
        sum += e;
      }
#pragma unroll
      for (int o = 8; o > 0; o >>= 1) sum += __shfl_xor(sum, o);
      float inv = 1.0f / sum;
#pragma unroll
      for (int n = 0; n < 4; ++n)
        Plds[rn * 64 + n * 16 + lr] = f2bf(vloc[n] * inv);
    }
  }

  __syncthreads();

  f32x4 o[4][2];
#pragma unroll
  for (int m = 0; m < 4; ++m)
#pragma unroll
    for (int j = 0; j < 2; ++j)
#pragma unroll
      for (int r2 = 0; r2 < 4; ++r2) o[m][j][r2] = 0.f;
#pragma unroll
  for (int ks = 0; ks < 2; ++ks) {
    short8 pf[4], vf[2];
#pragma unroll
    for (int m = 0; m < 4; ++m)
      pf[m] = *(const short8*)&Plds[(m * 16 + lr) * 64 + ks * 32 + lk];
#pragma unroll
    for (int j = 0; j < 2; ++j)
      vf[j] = *(const short8*)&Vt[(j * 16 + lr) * 64 + ks * 32 + lk];
#pragma unroll
    for (int m = 0; m < 4; ++m)
#pragma unroll
      for (int j = 0; j < 2; ++j)
        o[m][j] = __builtin_amdgcn_mfma_f32_16x16x32_bf16(pf[m], vf[j], o[m][j], 0, 0, 0);
  }

#pragma unroll
  for (int m = 0; m < 4; ++m) {
#pragma unroll
    for (int r2 = 0; r2 < 4; ++r2) {
      int rn = m * 16 + rgrp * 4 + r2;
      if (rn >= 10 && rn < 59) {
        size_t row = (size_t)i * 49 + (rn - 10);
        u16* op = outp + row * 512 + hd * 32;
        op[lr] = f2bf(o[m][0][r2]);
        op[16 + lr] = f2bf(o[m][1][r2]);
      }
    }
  }
}

// ---------- launch ----------
extern "C" void kernel_launch(void* const* d_in, const int* in_sizes, int n_in,
                              void* d_out, int out_size, void* d_ws, size_t ws_size,
                              hipStream_t stream) {
  const float* x = (const float*)d_in[0];
  const float* g1 = (const float*)d_in[1];
  const float* b1 = (const float*)d_in[2];
  const float* qkv_w = (const float*)d_in[3];
  const float* qkv_b = (const float*)d_in[4];
  const float* rpb = (const float*)d_in[5];
  const float* proj_w = (const float*)d_in[6];
  const float* proj_b = (const float*)d_in[7];
  const float* g2 = (const float*)d_in[8];
  const float* b2 = (const float*)d_in[9];
  const float* fc1_w = (const float*)d_in[10];
  const float* fc1_b = (const float*)d_in[11];
  const float* fc2_w = (const float*)d_in[12];
  const float* fc2_b = (const float*)d_in[13];
  float* out = (float*)d_out;

  char* ws = (char*)d_ws;
  u16* qkv_wb = (u16*)(ws + 0);
  u16* proj_wb = (u16*)(ws + 1572864);
  u16* fc1_wb = (u16*)(ws + 2097152);
  u16* fc2_wb = (u16*)(ws + 4194304);
  u16* xcat = (u16*)(ws + 6291456);
  u16* y = (u16*)(ws + 58327040);
  u16* attnv = (u16*)(ws + 214433792);
  float* xnew = (float*)(ws + 265814016);
  u16* hin = xcat;
  u16* hmid = y;

  cvt_bf16<<<768, 256, 0, stream>>>(qkv_w, qkv_wb, 196608);
  cvt_bf16<<<256, 256, 0, stream>>>(proj_w, proj_wb, 65536);
  cvt_bf16<<<1024, 256, 0, stream>>>(fc1_w, fc1_wb, 262144);
  cvt_bf16<<<1024, 256, 0, stream>>>(fc2_w, fc2_wb, 262144);

  ln1_kernel<<<12704, 256, 0, stream>>>(x, g1, b1, xcat);

  // QKV: 199 M-tiles of 256 (last partial; A overreads land in y, stores guarded) x 6 N
  gemm8p<0><<<199 * 6, 512, 0, stream>>>(xcat, qkv_wb, qkv_b, y, nullptr, nullptr,
                                         50816, 1536, 512, 6);

  attn_kernel<<<16384, 64, 0, stream>>>(y, rpb, attnv);

  gemm8p<1><<<196 * 2, 512, 0, stream>>>(attnv, proj_wb, proj_b, nullptr, xnew, x,
                                         50176, 512, 512, 2);

  ln2_kernel<<<12544, 256, 0, stream>>>(xnew, g2, b2, hin);

  gemm8p<2><<<196 * 8, 512, 0, stream>>>(hin, fc1_wb, fc1_b, hmid, nullptr, nullptr,
                                         50176, 2048, 512, 8);

  gemm8p<3><<<196 * 2, 512, 0, stream>>>(hmid, fc2_wb, fc2_b, nullptr, out, xnew,
                                         50176, 512, 2048, 2);
}

// Round 15
// 737.392 us; speedup vs baseline: 1.0526x; 1.0526x over previous
//
#include <hip/hip_runtime.h>
#include <stdint.h>

typedef unsigned short u16;
typedef unsigned int u32;
typedef __attribute__((ext_vector_type(8))) short short8;
typedef __attribute__((ext_vector_type(4))) float f32x4;

// ---------- helpers ----------
__device__ __forceinline__ u16 f2bf(float f) {
  u32 u = __builtin_bit_cast(u32, f);
  u32 r = u + 0x7FFFu + ((u >> 16) & 1u);
  return (u16)(r >> 16);
}

__device__ __forceinline__ void gl_lds16(const void* g, void* l) {
  __builtin_amdgcn_global_load_lds((__attribute__((address_space(1))) void*)g,
                                   (__attribute__((address_space(3))) void*)l,
                                   16, 0, 0);
}

// tanh-form GELU (~13 VALU inst; |err| <= ~3e-3, verified absmax unchanged)
__device__ __forceinline__ float gelu_fast(float v) {
  float u = 0.7978845608028654f * (v + 0.044715f * v * v * v);
  float a = fabsf(u);
  float e = __expf(-2.0f * a);
  float t = (1.0f - e) / (1.0f + e);     // tanh(|u|)
  float th = copysignf(t, u);
  return 0.5f * v * (1.0f + th);
}

// ---------- f32 -> bf16 convert (weights) ----------
__global__ __launch_bounds__(256) void cvt_bf16(const float* __restrict__ in,
                                                u16* __restrict__ out, int n4) {
  int idx = blockIdx.x * 256 + threadIdx.x;
  if (idx < n4) {
    float4 v = ((const float4*)in)[idx];
    u32 lo = (u32)f2bf(v.x) | ((u32)f2bf(v.y) << 16);
    u32 hi = (u32)f2bf(v.z) | ((u32)f2bf(v.w) << 16);
    ((uint2*)out)[idx] = make_uint2(lo, hi);
  }
}

// ---------- LN1 + roll + window partition gather ----------
__global__ __launch_bounds__(256) void ln1_kernel(const float* __restrict__ x,
                                                  const float* __restrict__ g,
                                                  const float* __restrict__ bta,
                                                  u16* __restrict__ xcat) {
  int wave = threadIdx.x >> 6, lane = threadIdx.x & 63;
  int row = blockIdx.x * 4 + wave;   // 0..50815
  const float* src;
  bool do_ln;
  if (row < 640) {
    int bb = row / 10, p = row - bb * 10;
    src = x + ((size_t)bb * 794 + p) * 512;
    do_ln = false;
  } else {
    int r2 = row - 640;
    int i = r2 / 49, t = r2 - i * 49;
    int bb = i >> 4, nw = i & 15;
    int tr = t / 7, tc = t - tr * 7;
    int hh = (nw >> 2) * 7 + tr + 3; if (hh >= 28) hh -= 28;
    int ww = (nw & 3) * 7 + tc + 3;  if (ww >= 28) ww -= 28;
    src = x + ((size_t)bb * 794 + 10 + hh * 28 + ww) * 512;
    do_ln = true;
  }
  float4 v0 = ((const float4*)src)[lane * 2];
  float4 v1 = ((const float4*)src)[lane * 2 + 1];
  float vals[8] = {v0.x, v0.y, v0.z, v0.w, v1.x, v1.y, v1.z, v1.w};
  u16 ob[8];
  if (do_ln) {
    float s = 0.f, s2 = 0.f;
#pragma unroll
    for (int j = 0; j < 8; ++j) { s += vals[j]; s2 += vals[j] * vals[j]; }
#pragma unroll
    for (int o = 32; o > 0; o >>= 1) { s += __shfl_xor(s, o); s2 += __shfl_xor(s2, o); }
    float mu = s * (1.0f / 512.0f);
    float var = s2 * (1.0f / 512.0f) - mu * mu;
    float inv = rsqrtf(var + 1e-5f);
    float4 ga = ((const float4*)g)[lane * 2], gb = ((const float4*)g)[lane * 2 + 1];
    float4 ba = ((const float4*)bta)[lane * 2], bb2 = ((const float4*)bta)[lane * 2 + 1];
    float gv[8] = {ga.x, ga.y, ga.z, ga.w, gb.x, gb.y, gb.z, gb.w};
    float bv[8] = {ba.x, ba.y, ba.z, ba.w, bb2.x, bb2.y, bb2.z, bb2.w};
#pragma unroll
    for (int j = 0; j < 8; ++j) ob[j] = f2bf((vals[j] - mu) * inv * gv[j] + bv[j]);
  } else {
#pragma unroll
    for (int j = 0; j < 8; ++j) ob[j] = f2bf(vals[j]);
  }
  u32 w0 = (u32)ob[0] | ((u32)ob[1] << 16);
  u32 w1 = (u32)ob[2] | ((u32)ob[3] << 16);
  u32 w2 = (u32)ob[4] | ((u32)ob[5] << 16);
  u32 w3 = (u32)ob[6] | ((u32)ob[7] << 16);
  ((uint4*)(xcat + (size_t)row * 512))[lane] = make_uint4(w0, w1, w2, w3);
}

// ---------- LN2 (plain rows) ----------
__global__ __launch_bounds__(256) void ln2_kernel(const float* __restrict__ xn,
                                                  const float* __restrict__ g,
                                                  const float* __restrict__ bta,
                                                  u16* __restrict__ outb) {
  int wave = threadIdx.x >> 6, lane = threadIdx.x & 63;
  size_t row = (size_t)blockIdx.x * 4 + wave;
  const float* src = xn + row * 512;
  float4 v0 = ((const float4*)src)[lane * 2];
  float4 v1 = ((const float4*)src)[lane * 2 + 1];
  float vals[8] = {v0.x, v0.y, v0.z, v0.w, v1.x, v1.y, v1.z, v1.w};
  float s = 0.f, s2 = 0.f;
#pragma unroll
  for (int j = 0; j < 8; ++j) { s += vals[j]; s2 += vals[j] * vals[j]; }
#pragma unroll
  for (int o = 32; o > 0; o >>= 1) { s += __shfl_xor(s, o); s2 += __shfl_xor(s2, o); }
  float mu = s * (1.0f / 512.0f);
  float var = s2 * (1.0f / 512.0f) - mu * mu;
  float inv = rsqrtf(var + 1e-5f);
  float4 ga = ((const float4*)g)[lane * 2], gb = ((const float4*)g)[lane * 2 + 1];
  float4 ba = ((const float4*)bta)[lane * 2], bb2 = ((const float4*)bta)[lane * 2 + 1];
  float gv[8] = {ga.x, ga.y, ga.z, ga.w, gb.x, gb.y, gb.z, gb.w};
  float bv[8] = {ba.x, ba.y, ba.z, ba.w, bb2.x, bb2.y, bb2.z, bb2.w};
  u16 ob[8];
#pragma unroll
  for (int j = 0; j < 8; ++j) ob[j] = f2bf((vals[j] - mu) * inv * gv[j] + bv[j]);
  u32 w0 = (u32)ob[0] | ((u32)ob[1] << 16);
  u32 w1 = (u32)ob[2] | ((u32)ob[3] << 16);
  u32 w2 = (u32)ob[4] | ((u32)ob[5] << 16);
  u32 w3 = (u32)ob[6] | ((u32)ob[7] << 16);
  ((uint4*)(outb + row * 512))[lane] = make_uint4(w0, w1, w2, w3);
}

// ---------- 256x256 bf16 GEMM, 8-phase template (fixed swizzle + const slots) ----------
// A: MxK row-major bf16, Wt: NxK row-major bf16 (B^T).
// 8 waves (2M x 4N), wave-tile 128x64, acc[8][4]. LDS: 8 half-slots x 16 KB (128 KB).
// half h = 4*kt + {0:A-ks0, 1:B-ks0, 2:A-ks1, 3:B-ks1}; slot = h&7 (compile-time via
// kt-unroll-by-2, P == 0 mod 8). Swizzle BOTH sides (rule 21), PROVEN axis (R4-R13,
// 0 conflicts): phys 16B-slot = slot ^ ((row>>1)&3). R14's (row&3) axis was a 4-way
// conflict (9.6M counted) -- fixed here.
// Phase: {bv[4] (mp0 only) + av[4] ds_read ; stage 1 half (2 gl_lds, const slot,
// running pA/pB + const offset) ; vmcnt(6)=3 halves in flight ; bar ; lgkm0 +
// sched_barrier(0) (rule 18) ; setprio(1) 16 MFMA setprio(0) ; bar}.
// Ledger (verified R14, unchanged): reads at phase p need halves <= p+1; vmcnt(6) at
// p-1 certifies halves <= p+1. Prologue stages halves 0..4; tail vmcnt 6,6,6,4,2,0,0,0.
#define PH(MB, RD_BV, SA, SB, DO_ST, SPTR, SOFF, SSLOT, VMC)                          \
  do {                                                                                \
    short8 av[4];                                                                     \
    if (RD_BV) {                                                                      \
      _Pragma("unroll") for (int n = 0; n < 4; ++n) {                                 \
        int row = wnW * 64 + n * 16 + lr;                                             \
        bv[n] = *(const short8*)&Hlds[SB][row * 32 + swzr];                           \
      }                                                                               \
    }                                                                                 \
    _Pragma("unroll") for (int mm = 0; mm < 4; ++mm) {                                \
      int row = wm * 128 + ((MB) + mm) * 16 + lr;                                     \
      av[mm] = *(const short8*)&Hlds[SA][row * 32 + swzr];                            \
    }                                                                                 \
    if (DO_ST) {                                                                      \
      u16* d = &Hlds[SSLOT][tid * 8];                                                 \
      gl_lds16((SPTR) + (SOFF), d);                                                   \
      gl_lds16((SPTR) + (SOFF) + halfK, d + 4096);                                    \
    }                                                                                 \
    asm volatile("s_waitcnt vmcnt(" #VMC ")" ::: "memory");                           \
    __builtin_amdgcn_s_barrier();                                                     \
    asm volatile("s_waitcnt lgkmcnt(0)" ::: "memory");                                \
    __builtin_amdgcn_sched_barrier(0);                                                \
    __builtin_amdgcn_s_setprio(1);                                                    \
    _Pragma("unroll") for (int mm = 0; mm < 4; ++mm)                                  \
      _Pragma("unroll") for (int n = 0; n < 4; ++n)                                   \
        acc[(MB) + mm][n] =                                                           \
            __builtin_amdgcn_mfma_f32_16x16x32_bf16(av[mm], bv[n], acc[(MB) + mm][n], \
                                                    0, 0, 0);                         \
    __builtin_amdgcn_s_setprio(0);                                                    \
    __builtin_amdgcn_s_barrier();                                                     \
  } while (0)

template <int EPI>
__global__ __launch_bounds__(512, 2) void gemm8p(const u16* __restrict__ A,
                                                 const u16* __restrict__ Wt,
                                                 const float* __restrict__ bias,
                                                 u16* __restrict__ outb,
                                                 float* __restrict__ outf,
                                                 const float* __restrict__ res,
                                                 int M, int N, int K, int Ntiles) {
  __shared__ __align__(16) u16 Hlds[8][8192];   // 128 KB
  const int tid = threadIdx.x;
  const int lane = tid & 63;
  const int wv = tid >> 6;            // 0..7
  const int wm = wv >> 2;             // 0..1  (M strip of 128)
  const int wnW = wv & 3;             // 0..3  (N strip of 64)
  const int lr = lane & 15;
  const int qh = lane >> 4;           // 0..3 (16B k-slot within 32-k half)
  const int swzr = (qh ^ ((lr >> 1) & 3)) << 3;   // PROVEN swizzle axis (0 conflicts)

  // bijective XCD swizzle (m204), N-fastest
  const int nwg = gridDim.x;
  const int qx = nwg >> 3, rx = nwg & 7;
  const int xcd = blockIdx.x & 7, local = blockIdx.x >> 3;
  const int swz = (xcd < rx ? xcd * (qx + 1) : rx * (qx + 1) + (xcd - rx) * qx) + local;
  const int mt = swz / Ntiles, nt = swz - mt * Ntiles;
  const int tm = mt << 8, tn = nt << 8;   // 256x256 tile

  f32x4 acc[8][4];
#pragma unroll
  for (int m = 0; m < 8; ++m)
#pragma unroll
    for (int n = 0; n < 4; ++n)
#pragma unroll
      for (int e = 0; e < 4; ++e) acc[m][n][e] = 0.f;

  // staging map: thread -> row srow (0..127; +128 for 2nd gl_lds), phys slot tid&3
  const int srow = tid >> 2;
  const int scol = ((tid & 3) ^ ((srow >> 1) & 3)) << 3;   // pre-swizzled source col
  const u16* Asrc = A + (size_t)(tm + srow) * K + scol;
  const u16* Bsrc = Wt + (size_t)(tn + srow) * K + scol;
  const size_t halfK = (size_t)128 * K;

  const int NT = K >> 6;   // K-tiles of 64: 8 (K=512) or 32 (K=2048); even

  // prologue: stage halves 0..4 (slots 0..4); vmcnt(6) certifies halves 0,1
  {
    gl_lds16(Asrc, &Hlds[0][tid * 8]);       gl_lds16(Asrc + halfK, &Hlds[0][tid * 8 + 4096]);
    gl_lds16(Bsrc, &Hlds[1][tid * 8]);       gl_lds16(Bsrc + halfK, &Hlds[1][tid * 8 + 4096]);
    gl_lds16(Asrc + 32, &Hlds[2][tid * 8]);  gl_lds16(Asrc + 32 + halfK, &Hlds[2][tid * 8 + 4096]);
    gl_lds16(Bsrc + 32, &Hlds[3][tid * 8]);  gl_lds16(Bsrc + 32 + halfK, &Hlds[3][tid * 8 + 4096]);
    gl_lds16(Asrc + 64, &Hlds[4][tid * 8]);  gl_lds16(Asrc + 64 + halfK, &Hlds[4][tid * 8 + 4096]);
    asm volatile("s_waitcnt vmcnt(6)" ::: "memory");
    __builtin_amdgcn_s_barrier();
  }

  short8 bv[4];
  const u16* pA = Asrc;
  const u16* pB = Bsrc;
  // full 2-kt bodies: kt = 0, 2, ..., NT-4  (stages halves 4kt+5 .. 4kt+12)
  for (int kt = 0; kt <= NT - 4; kt += 2) {
    PH(0, 1, 0, 1, 1, pB,  64, 5, 6);
    PH(4, 0, 0, 1, 1, pA,  96, 6, 6);
    PH(0, 1, 2, 3, 1, pB,  96, 7, 6);
    PH(4, 0, 2, 3, 1, pA, 128, 0, 6);
    PH(0, 1, 4, 5, 1, pB, 128, 1, 6);
    PH(4, 0, 4, 5, 1, pA, 160, 2, 6);
    PH(0, 1, 6, 7, 1, pB, 160, 3, 6);
    PH(4, 0, 6, 7, 1, pA, 192, 4, 6);
    pA += 128;
    pB += 128;
  }
  // tail: kt = NT-2, NT-1 (stages halves 4NT-3..4NT-1; vmcnt ramps 6,6,6,4,2,0,0,0)
  {
    PH(0, 1, 0, 1, 1, pB, 64, 5, 6);
    PH(4, 0, 0, 1, 1, pA, 96, 6, 6);
    PH(0, 1, 2, 3, 1, pB, 96, 7, 6);
    PH(4, 0, 2, 3, 0, pA, 0, 0, 4);
    PH(0, 1, 4, 5, 0, pA, 0, 0, 2);
    PH(4, 0, 4, 5, 0, pA, 0, 0, 0);
    PH(0, 1, 6, 7, 0, pA, 0, 0, 0);
    PH(4, 0, 6, 7, 0, pA, 0, 0, 0);
  }

  // ---------- epilogue ----------
  float bcol[4];
#pragma unroll
  for (int n = 0; n < 4; ++n) bcol[n] = bias[tn + wnW * 64 + n * 16 + lr];

#pragma unroll
  for (int m = 0; m < 8; ++m) {
#pragma unroll
    for (int r2 = 0; r2 < 4; ++r2) {
      int grow = tm + wm * 128 + m * 16 + qh * 4 + r2;
      if (grow >= M) continue;                    // QKV tail M-tile
      if (EPI == 1) {
        int i = grow / 49, t = grow - i * 49;
        int bb = i >> 4, nw = i & 15;
        int tr = t / 7, tc = t - tr * 7;
        int hh = (nw >> 2) * 7 + tr + 3; if (hh >= 28) hh -= 28;
        int ww = (nw & 3) * 7 + tc + 3;  if (ww >= 28) ww -= 28;
        size_t dstr = ((size_t)bb * 784 + hh * 28 + ww) * 512;
        size_t srcr = ((size_t)bb * 794 + 10 + hh * 28 + ww) * 512;
#pragma unroll
        for (int n = 0; n < 4; ++n) {
          int gcol = tn + wnW * 64 + n * 16 + lr;
          float v = acc[m][n][r2] + bcol[n];
          outf[dstr + gcol] = v + res[srcr + gcol];
        }
      } else {
#pragma unroll
        for (int n = 0; n < 4; ++n) {
          int gcol = tn + wnW * 64 + n * 16 + lr;
          float v = acc[m][n][r2] + bcol[n];
          if (EPI == 0) {
            outb[(size_t)grow * N + gcol] = f2bf(v);
          } else if (EPI == 2) {
            outb[(size_t)grow * N + gcol] = f2bf(gelu_fast(v));
          } else { // EPI == 3
            outf[(size_t)grow * N + gcol] = v + res[(size_t)grow * 512 + gcol];
          }
        }
      }
    }
  }
}

// ---------- fused window attention: one wave per (window, head) ----------
__global__ __launch_bounds__(64) void attn_kernel(const u16* __restrict__ Y,
                                                  const float* __restrict__ rpb,
                                                  u16* __restrict__ outp) {
  __shared__ __align__(16) u16 Plds[64 * 64];
  __shared__ __align__(16) u16 Vt[32 * 64];
  __shared__ float biasl[169];
  const int lane = threadIdx.x;
  const int i = blockIdx.x >> 4;
  const int hd = blockIdx.x & 15;
  const int bp = i & 63;           // reference quirk: prompt batch = i % B
  const int nw = i & 15;
  const int hi = nw >> 2, wi = nw & 3;
  const int lr = lane & 15;
  const int lk = (lane >> 4) * 8;

  for (int j = lane; j < 169; j += 64) biasl[j] = rpb[j * 16 + hd];

  short8 qf[4], kf[4];
#pragma unroll
  for (int m = 0; m < 4; ++m) {
    int t = m * 16 + lr;
    size_t r = (t < 10) ? (size_t)(bp * 10 + t) : (size_t)(640 + i * 49 + (t - 10));
    const u16* base = Y + r * 1536 + hd * 32 + lk;
    if (t < 59) {
      qf[m] = *(const short8*)(base);
      kf[m] = *(const short8*)(base + 512);
    } else {
#pragma unroll
      for (int e = 0; e < 8; ++e) { qf[m][e] = 0; kf[m][e] = 0; }
    }
  }
  {
    int t = lane;
    if (t < 59) {
      size_t r = (t < 10) ? (size_t)(bp * 10 + t) : (size_t)(640 + i * 49 + (t - 10));
      const u16* vp = Y + r * 1536 + 1024 + hd * 32;
      short8 vv0 = *(const short8*)(vp);
      short8 vv1 = *(const short8*)(vp + 8);
      short8 vv2 = *(const short8*)(vp + 16);
      short8 vv3 = *(const short8*)(vp + 24);
#pragma unroll
      for (int e = 0; e < 8; ++e) {
        Vt[e * 64 + t] = (u16)vv0[e];
        Vt[(8 + e) * 64 + t] = (u16)vv1[e];
        Vt[(16 + e) * 64 + t] = (u16)vv2[e];
        Vt[(24 + e) * 64 + t] = (u16)vv3[e];
      }
    } else {
      for (int d = 0; d < 32; ++d) Vt[d * 64 + t] = 0;
    }
  }

  f32x4 s[4][4];
#pragma unroll
  for (int m = 0; m < 4; ++m)
#pragma unroll
    for (int n = 0; n < 4; ++n)
#pragma unroll
      for (int r2 = 0; r2 < 4; ++r2) s[m][n][r2] = 0.f;
#pragma unroll
  for (int m = 0; m < 4; ++m)
#pragma unroll
    for (int n = 0; n < 4; ++n)
      s[m][n] = __builtin_amdgcn_mfma_f32_16x16x32_bf16(qf[m], kf[n], s[m][n], 0, 0, 0);

  __syncthreads();

  const float SCALE = 0.17677669529663687f;
  const int rgrp = lane >> 4;
#pragma unroll
  for (int m = 0; m < 4; ++m) {
#pragma unroll
    for (int r2 = 0; r2 < 4; ++r2) {
      int rn = m * 16 + rgrp * 4 + r2;   // query token
      int qa = rn - 10;
      int qra = qa / 7, qca = qa - qra * 7;
      int regA = 0;
      if (qa >= 0 && qa < 49) {
        int ha = hi * 7 + qra, wa = wi * 7 + qca;
        regA = (ha < 21 ? 0 : (ha < 25 ? 1 : 2)) * 3 + (wa < 21 ? 0 : (wa < 25 ? 1 : 2));
      }
      float vloc[4];
      float mx = -3.0e38f;
#pragma unroll
      for (int n = 0; n < 4; ++n) {
        int cm = n * 16 + lr;            // key token
        float v;
        if (cm >= 59) {
          v = -3.0e38f;
        } else {
          v = s[m][n][r2] * SCALE;
          if (rn >= 10 && rn < 59 && cm >= 10) {
            int kb = cm - 10;
            int krb = kb / 7, kcb = kb - krb * 7;
            v += biasl[(qra - krb + 6) * 13 + (qca - kcb + 6)];
            int hb = hi * 7 + krb, wb = wi * 7 + kcb;
            int regB = (hb < 21 ? 0 : (hb < 25 ? 1 : 2)) * 3 + (wb < 21 ? 0 : (wb < 25 ? 1 : 2));
            if (regA != regB) v -= 100.0f;
          }
        }
        vloc[n] = v;
        mx = fmaxf(mx, v);
      }
#pragma unroll
      for (int o = 8; o > 0; o >>= 1) mx = fmaxf(mx, __shfl_xor(mx, o));
      float sum = 0.f;
#pragma unroll
      for (int n = 0; n < 4; ++n) {
        float e = __expf(vloc[n] - mx);
        vloc[n] = e;
        sum += e;
      }
#pragma unroll
      for (int o = 8; o > 0; o >>= 1) sum += __shfl_xor(sum, o);
      float inv = 1.0f / sum;
#pragma unroll
      for (int n = 0; n < 4; ++n)
        Plds[rn * 64 + n * 16 + lr] = f2bf(vloc[n] * inv);
    }
  }

  __syncthreads();

  f32x4 o[4][2];
#pragma unroll
  for (int m = 0; m < 4; ++m)
#pragma unroll
    for (int j = 0; j < 2; ++j)
#pragma unroll
      for (int r2 = 0; r2 < 4; ++r2) o[m][j][r2] = 0.f;
#pragma unroll
  for (int ks = 0; ks < 2; ++ks) {
    short8 pf[4], vf[2];
#pragma unroll
    for (int m = 0; m < 4; ++m)
      pf[m] = *(const short8*)&Plds[(m * 16 + lr) * 64 + ks * 32 + lk];
#pragma unroll
    for (int j = 0; j < 2; ++j)
      vf[j] = *(const short8*)&Vt[(j * 16 + lr) * 64 + ks * 32 + lk];
#pragma unroll
    for (int m = 0; m < 4; ++m)
#pragma unroll
      for (int j = 0; j < 2; ++j)
        o[m][j] = __builtin_amdgcn_mfma_f32_16x16x32_bf16(pf[m], vf[j], o[m][j], 0, 0, 0);
  }

#pragma unroll
  for (int m = 0; m < 4; ++m) {
#pragma unroll
    for (int r2 = 0; r2 < 4; ++r2) {
      int rn = m * 16 + rgrp * 4 + r2;
      if (rn >= 10 && rn < 59) {
        size_t row = (size_t)i * 49 + (rn - 10);
        u16* op = outp + row * 512 + hd * 32;
        op[lr] = f2bf(o[m][0][r2]);
        op[16 + lr] = f2bf(o[m][1][r2]);
      }
    }
  }
}

// ---------- launch ----------
extern "C" void kernel_launch(void* const* d_in, const int* in_sizes, int n_in,
                              void* d_out, int out_size, void* d_ws, size_t ws_size,
                              hipStream_t stream) {
  const float* x = (const float*)d_in[0];
  const float* g1 = (const float*)d_in[1];
  const float* b1 = (const float*)d_in[2];
  const float* qkv_w = (const float*)d_in[3];
  const float* qkv_b = (const float*)d_in[4];
  const float* rpb = (const float*)d_in[5];
  const float* proj_w = (const float*)d_in[6];
  const float* proj_b = (const float*)d_in[7];
  const float* g2 = (const float*)d_in[8];
  const float* b2 = (const float*)d_in[9];
  const float* fc1_w = (const float*)d_in[10];
  const float* fc1_b = (const float*)d_in[11];
  const float* fc2_w = (const float*)d_in[12];
  const float* fc2_b = (const float*)d_in[13];
  float* out = (float*)d_out;

  char* ws = (char*)d_ws;
  u16* qkv_wb = (u16*)(ws + 0);
  u16* proj_wb = (u16*)(ws + 1572864);
  u16* fc1_wb = (u16*)(ws + 2097152);
  u16* fc2_wb = (u16*)(ws + 4194304);
  u16* xcat = (u16*)(ws + 6291456);
  u16* y = (u16*)(ws + 58327040);
  u16* attnv = (u16*)(ws + 214433792);
  float* xnew = (float*)(ws + 265814016);
  u16* hin = xcat;
  u16* hmid = y;

  cvt_bf16<<<768, 256, 0, stream>>>(qkv_w, qkv_wb, 196608);
  cvt_bf16<<<256, 256, 0, stream>>>(proj_w, proj_wb, 65536);
  cvt_bf16<<<1024, 256, 0, stream>>>(fc1_w, fc1_wb, 262144);
  cvt_bf16<<<1024, 256, 0, stream>>>(fc2_w, fc2_wb, 262144);

  ln1_kernel<<<12704, 256, 0, stream>>>(x, g1, b1, xcat);

  // QKV: 199 M-tiles of 256 (last partial; A overreads land in y, stores guarded) x 6 N
  gemm8p<0><<<199 * 6, 512, 0, stream>>>(xcat, qkv_wb, qkv_b, y, nullptr, nullptr,
                                         50816, 1536, 512, 6);

  attn_kernel<<<16384, 64, 0, stream>>>(y, rpb, attnv);

  gemm8p<1><<<196 * 2, 512, 0, stream>>>(attnv, proj_wb, proj_b, nullptr, xnew, x,
                                         50176, 512, 512, 2);

  ln2_kernel<<<12544, 256, 0, stream>>>(xnew, g2, b2, hin);

  gemm8p<2><<<196 * 8, 512, 0, stream>>>(hin, fc1_wb, fc1_b, hmid, nullptr, nullptr,
                                         50176, 2048, 512, 8);

  gemm8p<3><<<196 * 2, 512, 0, stream>>>(hmid, fc2_wb, fc2_b, nullptr, out, xnew,
                                         50176, 512, 2048, 2);
}